// Round 8
// baseline (95.177 us; speedup 1.0000x reference)
//
#include <hip/hip_runtime.h>

typedef __bf16 bf16x8 __attribute__((ext_vector_type(8)));
typedef float f32x4 __attribute__((ext_vector_type(4)));

// Problem constants
#define BB 4
#define CC 64
#define OO 64
#define HH 128
#define WW 128

// xs2 layout: [b][yy 0..129][xt 0..129][c 0..63] bf16, halo built in:
//   yy = y_in + 1 (rows 0 and 129 are zeros), xt = x_in + 1 (cols 0,129 zeros).
// Chunk = 16 B = 8 channels; 8 chunks per (yy,xt); 1040 chunks per row.
#define ROWCH (130 * 8)

typedef __attribute__((address_space(1))) const void GASV;
typedef __attribute__((address_space(3))) void LASV;

// ---------------------------------------------------------------------------
// Kernel 1 "prep": blocks 0..511 = prescale (one (b,y) row), 512..529 = prepack.
// prescale: float4 copy row into trans[64][132], then per-x poly scale + bf16
//   pack + contiguous 64B store to xs2[b][y+1][x+1][:]. Halo cols zeroed by
//   tid<16; blocks y==0 / y==127 also zero edge rows 0 / 129.
// prepack: aw16[(((og*18)+t)*64+l)*8+jj] = bf16 W[o][c][i][j], MFMA A-frag
//   order; t=(i*3+j)*2+ch, c=ch*32+(l>>4)*8+jj, o=og*16+(l&15).
// ---------------------------------------------------------------------------
__global__ __launch_bounds__(256) void prep_kernel(
    const float* __restrict__ in, const float* __restrict__ alpha,
    const float* __restrict__ w,
    const float* __restrict__ pa, const float* __restrict__ pb, const float* __restrict__ pc,
    unsigned short* __restrict__ xs, unsigned short* __restrict__ aw)
{
    __shared__ float trans[64][132];   // 33,792 B
    int tid = threadIdx.x;

    if (blockIdx.x >= 512) {
        // ---- prepack branch ----
        int gid = (blockIdx.x - 512) * 256 + tid;   // 0..4607
        if (gid >= 4608) return;
        int og  = gid / 1152;
        int rem = gid - og * 1152;
        int t = rem >> 6;
        int l = rem & 63;
        int q = l >> 4;
        int m = l & 15;
        int o  = og * 16 + m;
        int ij = t >> 1;
        int ch = t & 1;
        int i = ij / 3;
        int j = ij - i * 3;
        union { unsigned short u[8]; uint4 v; } pk;
#pragma unroll
        for (int jj = 0; jj < 8; ++jj) {
            int c = ch * 32 + q * 8 + jj;
            float wf = w[((o * CC + c) * 3 + i) * 3 + j];
            __bf16 h = (__bf16)wf;
            pk.u[jj] = __builtin_bit_cast(unsigned short, h);
        }
        ((uint4*)aw)[gid] = pk.v;
        return;
    }

    // ---- prescale branch ----
    int bid = blockIdx.x;             // 0..511
    int y   = bid & 127;
    int b   = bid >> 7;
    uint4* xsv = (uint4*)xs;

    // halo columns of this row (yy = y+1): xt=0 (chunks 0..7), xt=129 (8..15)
    if (tid < 16) {
        size_t rowbase = (size_t)(b * 130 + y + 1) * ROWCH;
        int xt = (tid < 8) ? 0 : 129;
        int g  = tid & 7;
        xsv[rowbase + (size_t)xt * 8 + g] = make_uint4(0u, 0u, 0u, 0u);
    }
    // edge rows: y==0 zeros row yy=0; y==127 zeros row yy=129
    if (y == 0 || y == 127) {
        size_t zbase = (size_t)(b * 130 + (y == 0 ? 0 : 129)) * ROWCH;
        for (int s = tid; s < ROWCH; s += 256)
            xsv[zbase + s] = make_uint4(0u, 0u, 0u, 0u);
    }

    // phase A: float4 copy 64c x 128x into trans
    int x16 = tid & 31;               // float4 index; x = x16*4
    int c8  = tid >> 5;               // 0..7
    const float* src = in + ((size_t)(b * CC) * HH + y) * WW;
#pragma unroll
    for (int k = 0; k < 8; ++k) {
        int c = c8 * 8 + k;
        float4 v = *(const float4*)(src + (size_t)c * HH * WW + x16 * 4);
        *(float4*)(&trans[c][x16 * 4]) = v;
    }
    __syncthreads();

    // phase B: scale + bf16 pack + contiguous 64B store at xt = x+1
    int xw = tid >> 1;                // 0..127
    int cg = tid & 1;                 // c-half
    float A  = *pa, Bc = *pb, Cc = *pc;
    float av = alpha[(b * HH + y) * WW + xw];
    float f  = (A * av + Bc) * av + Cc;
    union { unsigned short u[32]; uint4 v4[4]; } pk;
#pragma unroll
    for (int k = 0; k < 32; ++k) {
        __bf16 h = (__bf16)(trans[cg * 32 + k][xw] * f);
        pk.u[k] = __builtin_bit_cast(unsigned short, h);
    }
    uint4* dst = xsv + (size_t)(b * 130 + y + 1) * ROWCH + (size_t)(xw + 1) * 8 + cg * 4;
    dst[0] = pk.v4[0];
    dst[1] = pk.v4[1];
    dst[2] = pk.v4[2];
    dst[3] = pk.v4[3];
}

// ---------------------------------------------------------------------------
// Kernel 2: conv. One block per (b, y): 64 o x 128 x outputs, 4 waves,
// 2x4 mfma_f32_16x16x32_bf16 per wave.
//
// Staging: the 3-row window xs2[b][y..y+2][*][*] is one contiguous 49,920 B
// block (3120 chunks). 13 exec-masked global_load_lds width=16 issues per
// slot-group; LDS dest is lane-contiguous (wave-uniform base + lane*16).
// Swizzle (global side): LDS slot (xt, s) receives channel-chunk w=(s-xt)&7,
// so the unpadded stride-64-short tile reads conflict-free: K-loop reads
// slot (w+xt)&7 -> bank quads spread over all 8 residues (2-way = free).
// LDS: 49,920 B -> 2 blocks/CU.
// ---------------------------------------------------------------------------
__global__ __launch_bounds__(256, 2) void conv_kernel(
    const unsigned short* __restrict__ xs, const unsigned short* __restrict__ aw,
    const float* __restrict__ bias, float* __restrict__ out)
{
    __shared__ uint4 tile4[3120];   // 49,920 B
    unsigned short* tile = (unsigned short*)tile4;

    // XCD swizzle: xcd = bid&7 handles one (b, y-half) slab
    int n   = blockIdx.x;             // 0..511
    int xcd = n & 7;
    int idx = n >> 3;                 // 0..63
    int b   = xcd >> 1;
    int y   = (xcd & 1) * 64 + idx;
    int tid = threadIdx.x;
    int wv  = tid >> 6;
    int l   = tid & 63;

    // window base: rows yy = y, y+1, y+2  <=>  input rows y-1, y, y+1
    const uint4* win = (const uint4*)xs + (size_t)(b * 130 + y) * ROWCH;

    // async staging: 3120 chunks, rotate-swizzled on the global side
#pragma unroll
    for (int it = 0; it < 13; ++it) {
        int s_lin = it * 256 + tid;
        if (s_lin < 3120) {
            int rx = s_lin >> 3;          // r*130 + xt
            int s  = s_lin & 7;
            int xt = rx % 130;
            int wch = (s - xt) & 7;       // chunk stored at this slot
            const uint4* gp = win + rx * 8 + wch;
            // wave-uniform LDS base + implicit lane*16
            LASV* lp = (LASV*)(tile4 + it * 256 + wv * 64);
            __builtin_amdgcn_global_load_lds((GASV*)gp, lp, 16, 0, 0);
        }
    }
    __syncthreads();

    int oh = wv & 1;    // o-half: o in [oh*32, oh*32+32)
    int nh = wv >> 1;   // x-half: x in [nh*64, nh*64+64)
    int q  = l >> 4;
    int m  = l & 15;

    f32x4 acc[2][4];
#pragma unroll
    for (int ag = 0; ag < 2; ++ag)
#pragma unroll
        for (int nf = 0; nf < 4; ++nf)
            acc[ag][nf] = (f32x4){0.f, 0.f, 0.f, 0.f};

    const uint4* awv = (const uint4*)aw + (size_t)(oh * 2) * 18 * 64 + l;

#pragma unroll 3
    for (int ij = 0; ij < 9; ++ij) {
        const int i = ij / 3;
        const int j = ij - i * 3;
#pragma unroll
        for (int ch = 0; ch < 2; ++ch) {
            const int t = ij * 2 + ch;
            const int w = ch * 4 + q;     // wanted channel-chunk
            bf16x8 afrag[2], bfrag[4];
#pragma unroll
            for (int ag = 0; ag < 2; ++ag)
                afrag[ag] = __builtin_bit_cast(bf16x8, awv[(ag * 18 + t) * 64]);
#pragma unroll
            for (int nf = 0; nf < 4; ++nf) {
                int xt = nh * 64 + nf * 16 + m + j;   // xs2 column = x_out + j
                int sl = (w + xt) & 7;                // swizzled slot
                bfrag[nf] = __builtin_bit_cast(bf16x8,
                    *(const uint4*)(tile + ((i * 130 + xt) * 8 + sl) * 8));
            }
#pragma unroll
            for (int ag = 0; ag < 2; ++ag)
#pragma unroll
                for (int nf = 0; nf < 4; ++nf)
                    acc[ag][nf] = __builtin_amdgcn_mfma_f32_16x16x32_bf16(
                        afrag[ag], bfrag[nf], acc[ag][nf], 0, 0, 0);
        }
    }

    // epilogue: D layout (m89): o = q*4 + r, x = lane&15
#pragma unroll
    for (int ag = 0; ag < 2; ++ag) {
#pragma unroll
        for (int r = 0; r < 4; ++r) {
            int o = (oh * 2 + ag) * 16 + q * 4 + r;
            float bv = bias[o];
#pragma unroll
            for (int nf = 0; nf < 4; ++nf) {
                int x = nh * 64 + nf * 16 + m;
                out[((size_t)(b * OO + o) * HH + y) * WW + x] = acc[ag][nf][r] + bv;
            }
        }
    }
}

// ---------------------------------------------------------------------------
extern "C" void kernel_launch(void* const* d_in, const int* in_sizes, int n_in,
                              void* d_out, int out_size, void* d_ws, size_t ws_size,
                              hipStream_t stream) {
    const float* inputs = (const float*)d_in[0];
    const float* alpha  = (const float*)d_in[1];
    const float* weight = (const float*)d_in[2];
    const float* bias   = (const float*)d_in[3];
    const float* pa     = (const float*)d_in[4];
    const float* pb     = (const float*)d_in[5];
    const float* pc     = (const float*)d_in[6];
    float* out = (float*)d_out;

    unsigned short* aw = (unsigned short*)d_ws;                       // 73,728 B
    unsigned short* xs = (unsigned short*)((char*)d_ws + 131072);     // 8,652,800 B

    prep_kernel<<<512 + 18, 256, 0, stream>>>(inputs, alpha, weight, pa, pb, pc, xs, aw);
    conv_kernel<<<BB * HH, 256, 0, stream>>>(xs, aw, bias, out);
}